// Round 9
// baseline (2254.438 us; speedup 1.0000x reference)
//
#include <hip/hip_runtime.h>
#include <cmath>

#define HID 64
#define IN_C 128

__device__ __forceinline__ float rl(float v, int k) {
    return __uint_as_float(__builtin_amdgcn_readlane(__float_as_uint(v), k));
}
__device__ __forceinline__ float bflo(unsigned u) { return __uint_as_float(u << 16); }
__device__ __forceinline__ float bfhi(unsigned u) { return __uint_as_float(u & 0xffff0000u); }
__device__ __forceinline__ unsigned bfpack(float lo, float hi) {
    unsigned a = __float_as_uint(lo), b = __float_as_uint(hi);
    a = (a + 0x7fffu + ((a >> 16) & 1u)) >> 16;
    b = (b + 0x7fffu + ((b >> 16) & 1u)) & 0xffff0000u;
    return a | b;
}

// DPP add helpers (VALU pipe). CTRL: 0xB1 swap1, 0x4E swap2, 0x124 ror4, 0x128 ror8
template <int CTRL>
__device__ __forceinline__ float dppadd(float x) {
    int t = __builtin_amdgcn_update_dpp(0, __float_as_int(x), CTRL, 0xF, 0xF, true);
    return x + __int_as_float(t);
}
__device__ __forceinline__ float pairswap(float x) {
    int t = __builtin_amdgcn_update_dpp(0, __float_as_int(x), 0xB1, 0xF, 0xF, true);
    return __int_as_float(t);
}

// ---- CSR build ----------------------------------------------------------

__global__ void k_hist(const int* __restrict__ dst, int* __restrict__ counts, int E) {
    int e = blockIdx.x * blockDim.x + threadIdx.x;
    if (e < E) atomicAdd(&counts[dst[e]], 1);
}

__global__ void k_scan_block(const int* __restrict__ counts, int* __restrict__ row_ptr,
                             int* __restrict__ chunk_sums, int n) {
    __shared__ int s[1024];
    int i = blockIdx.x * 1024 + threadIdx.x;
    int v = (i < n) ? counts[i] : 0;
    s[threadIdx.x] = v;
    __syncthreads();
    for (int off = 1; off < 1024; off <<= 1) {
        int t = (threadIdx.x >= off) ? s[threadIdx.x - off] : 0;
        __syncthreads();
        s[threadIdx.x] += t;
        __syncthreads();
    }
    if (i < n) row_ptr[i] = s[threadIdx.x] - v;   // exclusive
    if (threadIdx.x == 1023) chunk_sums[blockIdx.x] = s[1023];
}

__global__ void k_scan_fix(int* __restrict__ row_ptr, const int* __restrict__ chunk_sums,
                           int n, int total) {
    __shared__ int base_s;
    if (threadIdx.x == 0) {
        int b = 0;
        for (int c = 0; c < (int)blockIdx.x; ++c) b += chunk_sums[c];
        base_s = b;
    }
    __syncthreads();
    int i = blockIdx.x * 1024 + threadIdx.x;
    if (i < n) row_ptr[i] += base_s;
    if (i == 0) row_ptr[n] = total;
}

__global__ void k_fill(const int* __restrict__ src, const int* __restrict__ dst,
                       const int* __restrict__ row_ptr, int* __restrict__ cursor,
                       int* __restrict__ col_idx, int E) {
    int e = blockIdx.x * blockDim.x + threadIdx.x;
    if (e < E) {
        int d = dst[e];
        int pos = row_ptr[d] + atomicAdd(&cursor[d], 1);
        col_idx[pos] = src[e];
    }
}

// ---- input projection: h0 slabs = relu(x @ lin0_w^T) --------------------
// Slab layout: S[cg][n] = 16B slice (channels 8cg..8cg+7, bf16 pair-packed).
__global__ __launch_bounds__(256) void k_lin0(const float* __restrict__ x,
                                              const float* __restrict__ w,
                                              const float* __restrict__ b,
                                              unsigned* __restrict__ S, int N) {
    __shared__ float Wt[IN_C * 65];
    for (int i = threadIdx.x; i < IN_C * HID; i += 256) {
        int o = i >> 7, k = i & 127;
        Wt[k * 65 + o] = w[i];
    }
    __syncthreads();
    size_t N4 = (size_t)N * 4;
    int lane = threadIdx.x & 63;
    int wid = (blockIdx.x * blockDim.x + threadIdx.x) >> 6;
    int nw = (gridDim.x * blockDim.x) >> 6;
    float bias = b[lane];
    size_t waddr = (size_t)(lane >> 3) * N4 + ((lane >> 1) & 3);
    for (int n0 = wid; n0 < N; n0 += 2 * nw) {
        int n1 = n0 + nw;
        bool v1 = n1 < N;
        int n1c = v1 ? n1 : n0;
        float xa0 = x[(size_t)n0 * IN_C + lane];
        float xa1 = x[(size_t)n0 * IN_C + 64 + lane];
        float xb0 = x[(size_t)n1c * IN_C + lane];
        float xb1 = x[(size_t)n1c * IN_C + 64 + lane];
        float acc0 = bias, acc1 = bias;
#pragma unroll
        for (int k = 0; k < 64; ++k) {
            float wv = Wt[k * 65 + lane];
            acc0 = fmaf(rl(xa0, k), wv, acc0);
            acc1 = fmaf(rl(xb0, k), wv, acc1);
        }
#pragma unroll
        for (int k = 0; k < 64; ++k) {
            float wv = Wt[(64 + k) * 65 + lane];
            acc0 = fmaf(rl(xa1, k), wv, acc0);
            acc1 = fmaf(rl(xb1, k), wv, acc1);
        }
        acc0 = fmaxf(acc0, 0.f);
        acc1 = fmaxf(acc1, 0.f);
        float p0 = pairswap(acc0);
        float p1 = pairswap(acc1);
        if ((lane & 1) == 0) {
            S[waddr + (size_t)n0 * 4] = bfpack(acc0, p0);
            if (v1) S[waddr + (size_t)n1 * 4] = bfpack(acc1, p1);
        }
    }
}

// ---- phase A: slab gather + residual -> z (bf16 rows) --------------------
// cg = blockIdx&7 (XCD round-robin): slab cg (1.6MB) stays L2-resident.
// lane = (ds = lane>>4 in 0..3 dst slot, es = lane&15 edge slot).
// Dual node-quads (A at n8, B at n8+4) for MLP. All reduce on VALU DPP.
__global__ __launch_bounds__(256) void k_aggr(const unsigned* __restrict__ Sin,
                                              const unsigned* __restrict__ h0S,
                                              unsigned* __restrict__ zrow,
                                              const int* __restrict__ row_ptr,
                                              const int* __restrict__ col_idx,
                                              int N) {
    int lane = threadIdx.x & 63;
    int es = lane & 15, ds = lane >> 4;
    int cg = blockIdx.x & 7;
    int grp = blockIdx.x >> 3;
    int ngrp = gridDim.x >> 3;
    int wv = threadIdx.x >> 6;
    int span = (N + ngrp - 1) / ngrp;
    int nbeg = grp * span;
    int nend = min(nbeg + span, N);
    const uint4* slab = (const uint4*)(Sin + (size_t)cg * N * 4);
    const uint4* h0sl = (const uint4*)(h0S + (size_t)cg * N * 4);
    uint4* zr = (uint4*)zrow;

    for (int n8 = nbeg + wv * 8; n8 < nend; n8 += 32) {
        int nA = n8 + ds;
        int nB = n8 + 4 + ds;
        bool vA = nA < nend, vB = nB < nend;
        int nAc = vA ? nA : nend - 1;
        int nBc = vB ? nB : nend - 1;
        int bA = row_ptr[nAc], eA = row_ptr[nAc + 1];
        int bB = row_ptr[nBc], eB = row_ptr[nBc + 1];
        int dA = eA - bA, dB = eB - bB;
        int lastA = (dA > 0) ? eA - 1 : 0;
        int lastB = (dB > 0) ? eB - 1 : 0;
        int baseA = (dA > 0) ? bA : 0;
        int baseB = (dB > 0) ? bB : 0;
        float aA[8], aB[8];
#pragma unroll
        for (int c = 0; c < 8; ++c) { aA[c] = 0.f; aB[c] = 0.f; }
        int rmax = max(dA, dB);
        for (int j = es; j < rmax; j += 16) {
            int pA = min(baseA + j, lastA);
            int pB = min(baseB + j, lastB);
            int iA = col_idx[pA];
            int iB = col_idx[pB];
            uint4 qA = slab[iA];
            uint4 qB = slab[iB];
            bool mA = j < dA, mB = j < dB;
            if (!mA) { qA.x = 0; qA.y = 0; qA.z = 0; qA.w = 0; }
            if (!mB) { qB.x = 0; qB.y = 0; qB.z = 0; qB.w = 0; }
            aA[0] += bflo(qA.x); aA[1] += bfhi(qA.x);
            aA[2] += bflo(qA.y); aA[3] += bfhi(qA.y);
            aA[4] += bflo(qA.z); aA[5] += bfhi(qA.z);
            aA[6] += bflo(qA.w); aA[7] += bfhi(qA.w);
            aB[0] += bflo(qB.x); aB[1] += bfhi(qB.x);
            aB[2] += bflo(qB.y); aB[3] += bfhi(qB.y);
            aB[4] += bflo(qB.z); aB[5] += bfhi(qB.z);
            aB[6] += bflo(qB.w); aB[7] += bfhi(qB.w);
        }
        // reduce over 16 lanes: offsets 1,2 (quad_perm), 4,8 (row_ror)
#pragma unroll
        for (int c = 0; c < 8; ++c) { aA[c] = dppadd<0xB1>(aA[c]);  aB[c] = dppadd<0xB1>(aB[c]); }
#pragma unroll
        for (int c = 0; c < 8; ++c) { aA[c] = dppadd<0x4E>(aA[c]);  aB[c] = dppadd<0x4E>(aB[c]); }
#pragma unroll
        for (int c = 0; c < 8; ++c) { aA[c] = dppadd<0x124>(aA[c]); aB[c] = dppadd<0x124>(aB[c]); }
#pragma unroll
        for (int c = 0; c < 8; ++c) { aA[c] = dppadd<0x128>(aA[c]); aB[c] = dppadd<0x128>(aB[c]); }

        uint4 hA = h0sl[nAc];
        uint4 hB = h0sl[nBc];
        float zA[8], zB[8];
        zA[0] = 0.9f * aA[0] + 0.1f * bflo(hA.x);
        zA[1] = 0.9f * aA[1] + 0.1f * bfhi(hA.x);
        zA[2] = 0.9f * aA[2] + 0.1f * bflo(hA.y);
        zA[3] = 0.9f * aA[3] + 0.1f * bfhi(hA.y);
        zA[4] = 0.9f * aA[4] + 0.1f * bflo(hA.z);
        zA[5] = 0.9f * aA[5] + 0.1f * bfhi(hA.z);
        zA[6] = 0.9f * aA[6] + 0.1f * bflo(hA.w);
        zA[7] = 0.9f * aA[7] + 0.1f * bfhi(hA.w);
        zB[0] = 0.9f * aB[0] + 0.1f * bflo(hB.x);
        zB[1] = 0.9f * aB[1] + 0.1f * bfhi(hB.x);
        zB[2] = 0.9f * aB[2] + 0.1f * bflo(hB.y);
        zB[3] = 0.9f * aB[3] + 0.1f * bfhi(hB.y);
        zB[4] = 0.9f * aB[4] + 0.1f * bflo(hB.z);
        zB[5] = 0.9f * aB[5] + 0.1f * bfhi(hB.z);
        zB[6] = 0.9f * aB[6] + 0.1f * bflo(hB.w);
        zB[7] = 0.9f * aB[7] + 0.1f * bfhi(hB.w);
        uint4 zqA, zqB;
        zqA.x = bfpack(zA[0], zA[1]); zqA.y = bfpack(zA[2], zA[3]);
        zqA.z = bfpack(zA[4], zA[5]); zqA.w = bfpack(zA[6], zA[7]);
        zqB.x = bfpack(zB[0], zB[1]); zqB.y = bfpack(zB[2], zB[3]);
        zqB.z = bfpack(zB[4], zB[5]); zqB.w = bfpack(zB[6], zB[7]);
        if (es == 0) {
            if (vA) zr[(size_t)nA * 8 + cg] = zqA;
            if (vB) zr[(size_t)nB * 8 + cg] = zqB;
        }
    }
}

// ---- phase B: dense r = relu(z @ W'), W' = (1-b)I + bW; out slabs --------
__global__ __launch_bounds__(256) void k_gemm(const uint4* __restrict__ zrow,
                                              unsigned* __restrict__ Sout,
                                              const float* __restrict__ W,
                                              float beta, int N) {
    __shared__ uint4 Wp[8 * 64];   // bf16x8 of W'[8k8+0..7][c]
    for (int idx = threadIdx.x; idx < 8 * 64; idx += 256) {
        int k8 = idx >> 6, c = idx & 63;
        float wv[8];
#pragma unroll
        for (int m = 0; m < 8; ++m) {
            int k = 8 * k8 + m;
            float v = beta * W[k * 64 + c];
            if (k == c) v += 1.f - beta;
            wv[m] = v;
        }
        uint4 p;
        p.x = bfpack(wv[0], wv[1]); p.y = bfpack(wv[2], wv[3]);
        p.z = bfpack(wv[4], wv[5]); p.w = bfpack(wv[6], wv[7]);
        Wp[idx] = p;
    }
    __syncthreads();

    size_t N4 = (size_t)N * 4;
    int lane = threadIdx.x & 63;
    int cg = lane & 7;
    int wid = (blockIdx.x * blockDim.x + threadIdx.x) >> 6;
    int nw = (gridDim.x * blockDim.x) >> 6;
    size_t waddr = (size_t)(lane >> 3) * N4 + ((lane >> 1) & 3);

    for (int n0 = 2 * wid; n0 < N; n0 += 2 * nw) {
        int n1 = n0 + 1;
        bool v1 = n1 < N;
        int n1c = v1 ? n1 : n0;
        uint4 zqA = zrow[(size_t)n0 * 8 + cg];
        uint4 zqB = zrow[(size_t)n1c * 8 + cg];
        float zA[8], zB[8];
        zA[0] = bflo(zqA.x); zA[1] = bfhi(zqA.x);
        zA[2] = bflo(zqA.y); zA[3] = bfhi(zqA.y);
        zA[4] = bflo(zqA.z); zA[5] = bfhi(zqA.z);
        zA[6] = bflo(zqA.w); zA[7] = bfhi(zqA.w);
        zB[0] = bflo(zqB.x); zB[1] = bfhi(zqB.x);
        zB[2] = bflo(zqB.y); zB[3] = bfhi(zqB.y);
        zB[4] = bflo(zqB.z); zB[5] = bfhi(zqB.z);
        zB[6] = bflo(zqB.w); zB[7] = bfhi(zqB.w);

        float gA0 = 0.f, gA1 = 0.f, gA2 = 0.f, gA3 = 0.f;
        float gB0 = 0.f, gB1 = 0.f, gB2 = 0.f, gB3 = 0.f;
#pragma unroll
        for (int k8 = 0; k8 < 8; ++k8) {
            uint4 wp = Wp[k8 * 64 + lane];
            gA0 = fmaf(rl(zA[0], k8), bflo(wp.x), gA0);
            gA1 = fmaf(rl(zA[1], k8), bfhi(wp.x), gA1);
            gA2 = fmaf(rl(zA[2], k8), bflo(wp.y), gA2);
            gA3 = fmaf(rl(zA[3], k8), bfhi(wp.y), gA3);
            gA0 = fmaf(rl(zA[4], k8), bflo(wp.z), gA0);
            gA1 = fmaf(rl(zA[5], k8), bfhi(wp.z), gA1);
            gA2 = fmaf(rl(zA[6], k8), bflo(wp.w), gA2);
            gA3 = fmaf(rl(zA[7], k8), bfhi(wp.w), gA3);
            gB0 = fmaf(rl(zB[0], k8), bflo(wp.x), gB0);
            gB1 = fmaf(rl(zB[1], k8), bfhi(wp.x), gB1);
            gB2 = fmaf(rl(zB[2], k8), bflo(wp.y), gB2);
            gB3 = fmaf(rl(zB[3], k8), bfhi(wp.y), gB3);
            gB0 = fmaf(rl(zB[4], k8), bflo(wp.z), gB0);
            gB1 = fmaf(rl(zB[5], k8), bfhi(wp.z), gB1);
            gB2 = fmaf(rl(zB[6], k8), bflo(wp.w), gB2);
            gB3 = fmaf(rl(zB[7], k8), bfhi(wp.w), gB3);
        }
        float rA = fmaxf((gA0 + gA1) + (gA2 + gA3), 0.f);
        float rB = fmaxf((gB0 + gB1) + (gB2 + gB3), 0.f);
        float rAn = pairswap(rA);
        float rBn = pairswap(rB);
        if ((lane & 1) == 0) {
            Sout[waddr + (size_t)n0 * 4] = bfpack(rA, rAn);
            if (v1) Sout[waddr + (size_t)n1 * 4] = bfpack(rB, rBn);
        }
    }
}

// ---- output projection: out = h @ lin1_w^T + b (slab input) --------------
__global__ __launch_bounds__(256) void k_lin1(const unsigned* __restrict__ S,
                                              const float* __restrict__ w,
                                              const float* __restrict__ b,
                                              float* __restrict__ out, int N) {
    __shared__ float Wt[HID * 65];
    for (int i = threadIdx.x; i < HID * HID; i += 256) {
        int o = i >> 6, k = i & 63;
        Wt[k * 65 + o] = w[i];
    }
    __syncthreads();
    size_t N4 = (size_t)N * 4;
    int lane = threadIdx.x & 63;
    int wid = (blockIdx.x * blockDim.x + threadIdx.x) >> 6;
    int nw = (gridDim.x * blockDim.x) >> 6;
    float bias = b[lane];
    size_t raddr = (size_t)(lane >> 3) * N4 + ((lane >> 1) & 3);
    for (int n0 = wid; n0 < N; n0 += 2 * nw) {
        int n1 = n0 + nw;
        bool v1 = n1 < N;
        int n1c = v1 ? n1 : n0;
        unsigned ua = S[raddr + (size_t)n0 * 4];
        unsigned ub = S[raddr + (size_t)n1c * 4];
        float ha = (lane & 1) ? bfhi(ua) : bflo(ua);
        float hb = (lane & 1) ? bfhi(ub) : bflo(ub);
        float acc0 = bias, acc1 = bias;
#pragma unroll
        for (int k = 0; k < 64; ++k) {
            float wv = Wt[k * 65 + lane];
            acc0 = fmaf(rl(ha, k), wv, acc0);
            acc1 = fmaf(rl(hb, k), wv, acc1);
        }
        out[(size_t)n0 * HID + lane] = acc0;
        if (v1) out[(size_t)n1 * HID + lane] = acc1;
    }
}

extern "C" void kernel_launch(void* const* d_in, const int* in_sizes, int n_in,
                              void* d_out, int out_size, void* d_ws, size_t ws_size,
                              hipStream_t stream) {
    const float* x      = (const float*)d_in[0];
    const int*   ei     = (const int*)d_in[1];
    const float* lin0_w = (const float*)d_in[2];
    const float* lin0_b = (const float*)d_in[3];
    const float* lin1_w = (const float*)d_in[4];
    const float* lin1_b = (const float*)d_in[5];
    const float* conv_w = (const float*)d_in[6];

    int N = in_sizes[0] / IN_C;
    int E = in_sizes[1] / 2;
    const int* src = ei;
    const int* dst = ei + E;

    // slab state buffers: 8 slabs x N x 4 uints = N*32 uints each
    unsigned* h0S = (unsigned*)d_ws;
    unsigned* SA  = h0S + (size_t)N * 32;
    unsigned* SB  = SA + (size_t)N * 32;
    int* row_ptr    = (int*)(SB + (size_t)N * 32);
    int* cursor     = row_ptr + (N + 1);
    int* col_idx    = cursor + N;
    int* chunk_sums = col_idx + E;
    // z buffer lives in d_out (dead until k_lin1 fully rewrites d_out)
    unsigned* Z = (unsigned*)d_out;

    int nch = (N + 1023) / 1024;

    // CSR build
    hipMemsetAsync(cursor, 0, (size_t)N * sizeof(int), stream);
    k_hist<<<(E + 255) / 256, 256, 0, stream>>>(dst, cursor, E);
    k_scan_block<<<nch, 1024, 0, stream>>>(cursor, row_ptr, chunk_sums, N);
    k_scan_fix<<<nch, 1024, 0, stream>>>(row_ptr, chunk_sums, N, E);
    hipMemsetAsync(cursor, 0, (size_t)N * sizeof(int), stream);
    k_fill<<<(E + 255) / 256, 256, 0, stream>>>(src, dst, row_ptr, cursor, col_idx, E);

    // input projection -> h0 slabs
    k_lin0<<<1024, 256, 0, stream>>>(x, lin0_w, lin0_b, h0S, N);

    // 16 layers: slab-gather (z) then dense GEMM (next slab state)
    const unsigned* cur = h0S;
    for (int l = 0; l < 16; ++l) {
        float beta = (float)log(0.5 / (double)(l + 1) + 1.0);
        unsigned* nxt = (l & 1) ? SB : SA;
        k_aggr<<<1024, 256, 0, stream>>>(cur, h0S, Z, row_ptr, col_idx, N);
        k_gemm<<<2048, 256, 0, stream>>>((const uint4*)Z, nxt,
                                         conv_w + (size_t)l * HID * HID, beta, N);
        cur = nxt;
    }

    // output projection (reads final slab state, overwrites d_out)
    k_lin1<<<1024, 256, 0, stream>>>(cur, lin1_w, lin1_b, (float*)d_out, N);
}

// Round 10
// 1525.794 us; speedup vs baseline: 1.4776x; 1.4776x over previous
//
#include <hip/hip_runtime.h>
#include <cmath>

#define HID 64
#define IN_C 128

__device__ __forceinline__ float rl(float v, int k) {
    return __uint_as_float(__builtin_amdgcn_readlane(__float_as_uint(v), k));
}
__device__ __forceinline__ float bflo(unsigned u) { return __uint_as_float(u << 16); }
__device__ __forceinline__ float bfhi(unsigned u) { return __uint_as_float(u & 0xffff0000u); }
__device__ __forceinline__ unsigned bfpack(float lo, float hi) {
    unsigned a = __float_as_uint(lo), b = __float_as_uint(hi);
    a = (a + 0x7fffu + ((a >> 16) & 1u)) >> 16;
    b = (b + 0x7fffu + ((b >> 16) & 1u)) & 0xffff0000u;
    return a | b;
}

// ---- VALU cross-lane helpers --------------------------------------------
__device__ __forceinline__ float xadd8(float x) {
    int t = __builtin_amdgcn_update_dpp(0, __float_as_int(x), 0x128, 0xF, 0xF, true);
    return x + __int_as_float(t);
}
#if __has_builtin(__builtin_amdgcn_permlane16_swap)
typedef unsigned uvec2 __attribute__((ext_vector_type(2)));
__device__ __forceinline__ float xadd16(float x) {
    uvec2 r = __builtin_amdgcn_permlane16_swap(__float_as_uint(x), __float_as_uint(x), false, false);
    return __uint_as_float(r[0]) + __uint_as_float(r[1]);
}
#else
__device__ __forceinline__ float xadd16(float x) { return x + __shfl_xor(x, 16); }
#endif
#if __has_builtin(__builtin_amdgcn_permlane32_swap)
typedef unsigned uvec2b __attribute__((ext_vector_type(2)));
__device__ __forceinline__ float xadd32(float x) {
    uvec2b r = __builtin_amdgcn_permlane32_swap(__float_as_uint(x), __float_as_uint(x), false, false);
    return __uint_as_float(r[0]) + __uint_as_float(r[1]);
}
#else
__device__ __forceinline__ float xadd32(float x) { return x + __shfl_xor(x, 32); }
#endif
__device__ __forceinline__ float pairswap(float x) {
    int t = __builtin_amdgcn_update_dpp(0, __float_as_int(x), 0xB1, 0xF, 0xF, true);
    return __int_as_float(t);
}

// ---- CSR build ----------------------------------------------------------

__global__ void k_hist(const int* __restrict__ dst, int* __restrict__ counts, int E) {
    int e = blockIdx.x * blockDim.x + threadIdx.x;
    if (e < E) atomicAdd(&counts[dst[e]], 1);
}

__global__ void k_scan_block(const int* __restrict__ counts, int* __restrict__ row_ptr,
                             int* __restrict__ chunk_sums, int n) {
    __shared__ int s[1024];
    int i = blockIdx.x * 1024 + threadIdx.x;
    int v = (i < n) ? counts[i] : 0;
    s[threadIdx.x] = v;
    __syncthreads();
    for (int off = 1; off < 1024; off <<= 1) {
        int t = (threadIdx.x >= off) ? s[threadIdx.x - off] : 0;
        __syncthreads();
        s[threadIdx.x] += t;
        __syncthreads();
    }
    if (i < n) row_ptr[i] = s[threadIdx.x] - v;   // exclusive
    if (threadIdx.x == 1023) chunk_sums[blockIdx.x] = s[1023];
}

__global__ void k_scan_fix(int* __restrict__ row_ptr, const int* __restrict__ chunk_sums,
                           int n, int total) {
    __shared__ int base_s;
    if (threadIdx.x == 0) {
        int b = 0;
        for (int c = 0; c < (int)blockIdx.x; ++c) b += chunk_sums[c];
        base_s = b;
    }
    __syncthreads();
    int i = blockIdx.x * 1024 + threadIdx.x;
    if (i < n) row_ptr[i] += base_s;
    if (i == 0) row_ptr[n] = total;
}

__global__ void k_fill(const int* __restrict__ src, const int* __restrict__ dst,
                       const int* __restrict__ row_ptr, int* __restrict__ cursor,
                       int* __restrict__ col_idx, int E) {
    int e = blockIdx.x * blockDim.x + threadIdx.x;
    if (e < E) {
        int d = dst[e];
        int pos = row_ptr[d] + atomicAdd(&cursor[d], 1);
        col_idx[pos] = src[e];
    }
}

// ---- input projection: h0(bf16) = relu(x @ lin0_w^T) --------------------
__global__ __launch_bounds__(256) void k_lin0(const float* __restrict__ x,
                                              const float* __restrict__ w,
                                              const float* __restrict__ b,
                                              unsigned* __restrict__ h0, int N) {
    __shared__ float Wt[IN_C * 65];
    for (int i = threadIdx.x; i < IN_C * HID; i += 256) {
        int o = i >> 7, k = i & 127;
        Wt[k * 65 + o] = w[i];
    }
    __syncthreads();
    int lane = threadIdx.x & 63;
    int wid = (blockIdx.x * blockDim.x + threadIdx.x) >> 6;
    int nw = (gridDim.x * blockDim.x) >> 6;
    float bias = b[lane];
    for (int n0 = wid; n0 < N; n0 += 2 * nw) {
        int n1 = n0 + nw;
        bool v1 = n1 < N;
        int n1c = v1 ? n1 : n0;
        float xa0 = x[(size_t)n0 * IN_C + lane];
        float xa1 = x[(size_t)n0 * IN_C + 64 + lane];
        float xb0 = x[(size_t)n1c * IN_C + lane];
        float xb1 = x[(size_t)n1c * IN_C + 64 + lane];
        float acc0 = bias, acc1 = bias;
#pragma unroll
        for (int k = 0; k < 64; ++k) {
            float wv = Wt[k * 65 + lane];
            acc0 = fmaf(rl(xa0, k), wv, acc0);
            acc1 = fmaf(rl(xb0, k), wv, acc1);
        }
#pragma unroll
        for (int k = 0; k < 64; ++k) {
            float wv = Wt[(64 + k) * 65 + lane];
            acc0 = fmaf(rl(xa1, k), wv, acc0);
            acc1 = fmaf(rl(xb1, k), wv, acc1);
        }
        acc0 = fmaxf(acc0, 0.f);
        acc1 = fmaxf(acc1, 0.f);
        float p0 = pairswap(acc0);
        float p1 = pairswap(acc1);
        if ((lane & 1) == 0) {
            h0[(size_t)n0 * 32 + (lane >> 1)] = bfpack(acc0, p0);
            if (v1) h0[(size_t)n1 * 32 + (lane >> 1)] = bfpack(acc1, p1);
        }
    }
}

// ---- fused GCN2 layer: 4-node deep-pipelined gather ----------------------
// Per outer iter a wave owns 4 nodes. All 16 index loads then all 16 row
// gathers (16 KB) are issued before any consumption -> ~8x bytes in flight.
// Degree <= 32 covered unconditionally; rare tail loop beyond. W'=(1-b)I+bW.
__device__ __forceinline__ void mask4(uint4& q, bool v) {
    q.x = v ? q.x : 0u; q.y = v ? q.y : 0u; q.z = v ? q.z : 0u; q.w = v ? q.w : 0u;
}
__device__ __forceinline__ void acc8(float* a, const uint4& q) {
    a[0] += bflo(q.x); a[1] += bfhi(q.x);
    a[2] += bflo(q.y); a[3] += bfhi(q.y);
    a[4] += bflo(q.z); a[5] += bfhi(q.z);
    a[6] += bflo(q.w); a[7] += bfhi(q.w);
}

__global__ __launch_bounds__(256) void k_layer(const uint4* __restrict__ hin,
                                               const uint4* __restrict__ h0,
                                               unsigned* __restrict__ hout,
                                               const float* __restrict__ W,
                                               const int* __restrict__ row_ptr,
                                               const int* __restrict__ col_idx,
                                               float beta, int N) {
    __shared__ uint4 Wp[8 * 64];   // bf16x8 of W'[8k8+0..7][c]
    for (int idx = threadIdx.x; idx < 8 * 64; idx += 256) {
        int k8 = idx >> 6, c = idx & 63;
        float wv[8];
#pragma unroll
        for (int m = 0; m < 8; ++m) {
            int k = 8 * k8 + m;
            float v = beta * W[k * 64 + c];
            if (k == c) v += 1.f - beta;
            wv[m] = v;
        }
        uint4 p;
        p.x = bfpack(wv[0], wv[1]); p.y = bfpack(wv[2], wv[3]);
        p.z = bfpack(wv[4], wv[5]); p.w = bfpack(wv[6], wv[7]);
        Wp[idx] = p;
    }
    __syncthreads();

    int lane = threadIdx.x & 63;
    int sub = lane >> 3;   // edge slot 0..7
    int cg = lane & 7;     // channel quad 0..7
    int wid = (blockIdx.x * blockDim.x + threadIdx.x) >> 6;
    int nw = (gridDim.x * blockDim.x) >> 6;

    for (int n0 = wid; n0 < N; n0 += 4 * nw) {
        int n1 = n0 + nw, n2 = n0 + 2 * nw, n3 = n0 + 3 * nw;
        bool v1 = n1 < N, v2 = n2 < N, v3 = n3 < N;
        int m1 = v1 ? n1 : n0, m2 = v2 ? n2 : n0, m3 = v3 ? n3 : n0;
        int b0 = row_ptr[n0], e0 = row_ptr[n0 + 1];
        int b1 = row_ptr[m1], e1 = row_ptr[m1 + 1];
        int b2 = row_ptr[m2], e2 = row_ptr[m2 + 1];
        int b3 = row_ptr[m3], e3 = row_ptr[m3 + 1];
        int d0 = e0 - b0, d1 = v1 ? e1 - b1 : 0, d2 = v2 ? e2 - b2 : 0, d3 = v3 ? e3 - b3 : 0;
        int L0 = b0 + max(d0 - 1, 0), L1 = b1 + max(d1 - 1, 0);
        int L2 = b2 + max(d2 - 1, 0), L3 = b3 + max(d3 - 1, 0);
        // residual rows early (independent)
        uint4 hq0 = h0[(size_t)n0 * 8 + cg];
        uint4 hq1 = h0[(size_t)m1 * 8 + cg];
        uint4 hq2 = h0[(size_t)m2 * 8 + cg];
        uint4 hq3 = h0[(size_t)m3 * 8 + cg];
        // 16 independent index loads (4 rounds x 4 nodes)
        int i00 = col_idx[min(b0 + sub, L0)];
        int i01 = col_idx[min(b0 + 8 + sub, L0)];
        int i02 = col_idx[min(b0 + 16 + sub, L0)];
        int i03 = col_idx[min(b0 + 24 + sub, L0)];
        int i10 = col_idx[min(b1 + sub, L1)];
        int i11 = col_idx[min(b1 + 8 + sub, L1)];
        int i12 = col_idx[min(b1 + 16 + sub, L1)];
        int i13 = col_idx[min(b1 + 24 + sub, L1)];
        int i20 = col_idx[min(b2 + sub, L2)];
        int i21 = col_idx[min(b2 + 8 + sub, L2)];
        int i22 = col_idx[min(b2 + 16 + sub, L2)];
        int i23 = col_idx[min(b2 + 24 + sub, L2)];
        int i30 = col_idx[min(b3 + sub, L3)];
        int i31 = col_idx[min(b3 + 8 + sub, L3)];
        int i32 = col_idx[min(b3 + 16 + sub, L3)];
        int i33 = col_idx[min(b3 + 24 + sub, L3)];
        // 16 independent row gathers (16 KB in flight)
        uint4 q00 = hin[(size_t)i00 * 8 + cg];
        uint4 q01 = hin[(size_t)i01 * 8 + cg];
        uint4 q02 = hin[(size_t)i02 * 8 + cg];
        uint4 q03 = hin[(size_t)i03 * 8 + cg];
        uint4 q10 = hin[(size_t)i10 * 8 + cg];
        uint4 q11 = hin[(size_t)i11 * 8 + cg];
        uint4 q12 = hin[(size_t)i12 * 8 + cg];
        uint4 q13 = hin[(size_t)i13 * 8 + cg];
        uint4 q20 = hin[(size_t)i20 * 8 + cg];
        uint4 q21 = hin[(size_t)i21 * 8 + cg];
        uint4 q22 = hin[(size_t)i22 * 8 + cg];
        uint4 q23 = hin[(size_t)i23 * 8 + cg];
        uint4 q30 = hin[(size_t)i30 * 8 + cg];
        uint4 q31 = hin[(size_t)i31 * 8 + cg];
        uint4 q32 = hin[(size_t)i32 * 8 + cg];
        uint4 q33 = hin[(size_t)i33 * 8 + cg];

        float a0[8], a1[8], a2[8], a3[8];
#pragma unroll
        for (int c = 0; c < 8; ++c) { a0[c] = 0.f; a1[c] = 0.f; a2[c] = 0.f; a3[c] = 0.f; }
        mask4(q00, sub < d0); mask4(q01, 8 + sub < d0);
        mask4(q02, 16 + sub < d0); mask4(q03, 24 + sub < d0);
        acc8(a0, q00); acc8(a0, q01); acc8(a0, q02); acc8(a0, q03);
        mask4(q10, sub < d1); mask4(q11, 8 + sub < d1);
        mask4(q12, 16 + sub < d1); mask4(q13, 24 + sub < d1);
        acc8(a1, q10); acc8(a1, q11); acc8(a1, q12); acc8(a1, q13);
        mask4(q20, sub < d2); mask4(q21, 8 + sub < d2);
        mask4(q22, 16 + sub < d2); mask4(q23, 24 + sub < d2);
        acc8(a2, q20); acc8(a2, q21); acc8(a2, q22); acc8(a2, q23);
        mask4(q30, sub < d3); mask4(q31, 8 + sub < d3);
        mask4(q32, 16 + sub < d3); mask4(q33, 24 + sub < d3);
        acc8(a3, q30); acc8(a3, q31); acc8(a3, q32); acc8(a3, q33);

        // rare tail (degree > 32)
        int dmax = max(max(d0, d1), max(d2, d3));
        for (int j = 32; j < dmax; j += 8) {
            int t0 = col_idx[min(b0 + j + sub, L0)];
            int t1 = col_idx[min(b1 + j + sub, L1)];
            int t2 = col_idx[min(b2 + j + sub, L2)];
            int t3 = col_idx[min(b3 + j + sub, L3)];
            uint4 p0 = hin[(size_t)t0 * 8 + cg];
            uint4 p1 = hin[(size_t)t1 * 8 + cg];
            uint4 p2 = hin[(size_t)t2 * 8 + cg];
            uint4 p3 = hin[(size_t)t3 * 8 + cg];
            mask4(p0, j + sub < d0); mask4(p1, j + sub < d1);
            mask4(p2, j + sub < d2); mask4(p3, j + sub < d3);
            acc8(a0, p0); acc8(a1, p1); acc8(a2, p2); acc8(a3, p3);
        }

        // reduce over 8 edge slots — VALU DPP/permlane
#pragma unroll
        for (int c = 0; c < 8; ++c) {
            a0[c] = xadd8(a0[c]); a1[c] = xadd8(a1[c]);
            a2[c] = xadd8(a2[c]); a3[c] = xadd8(a3[c]);
        }
#pragma unroll
        for (int c = 0; c < 8; ++c) {
            a0[c] = xadd16(a0[c]); a1[c] = xadd16(a1[c]);
            a2[c] = xadd16(a2[c]); a3[c] = xadd16(a3[c]);
        }
#pragma unroll
        for (int c = 0; c < 8; ++c) {
            a0[c] = xadd32(a0[c]); a1[c] = xadd32(a1[c]);
            a2[c] = xadd32(a2[c]); a3[c] = xadd32(a3[c]);
        }

        // residual: z = 0.9*agg + 0.1*h0
        float z0[8], z1[8], z2[8], z3[8];
        z0[0] = 0.9f * a0[0] + 0.1f * bflo(hq0.x);
        z0[1] = 0.9f * a0[1] + 0.1f * bfhi(hq0.x);
        z0[2] = 0.9f * a0[2] + 0.1f * bflo(hq0.y);
        z0[3] = 0.9f * a0[3] + 0.1f * bfhi(hq0.y);
        z0[4] = 0.9f * a0[4] + 0.1f * bflo(hq0.z);
        z0[5] = 0.9f * a0[5] + 0.1f * bfhi(hq0.z);
        z0[6] = 0.9f * a0[6] + 0.1f * bflo(hq0.w);
        z0[7] = 0.9f * a0[7] + 0.1f * bfhi(hq0.w);
        z1[0] = 0.9f * a1[0] + 0.1f * bflo(hq1.x);
        z1[1] = 0.9f * a1[1] + 0.1f * bfhi(hq1.x);
        z1[2] = 0.9f * a1[2] + 0.1f * bflo(hq1.y);
        z1[3] = 0.9f * a1[3] + 0.1f * bfhi(hq1.y);
        z1[4] = 0.9f * a1[4] + 0.1f * bflo(hq1.z);
        z1[5] = 0.9f * a1[5] + 0.1f * bfhi(hq1.z);
        z1[6] = 0.9f * a1[6] + 0.1f * bflo(hq1.w);
        z1[7] = 0.9f * a1[7] + 0.1f * bfhi(hq1.w);
        z2[0] = 0.9f * a2[0] + 0.1f * bflo(hq2.x);
        z2[1] = 0.9f * a2[1] + 0.1f * bfhi(hq2.x);
        z2[2] = 0.9f * a2[2] + 0.1f * bflo(hq2.y);
        z2[3] = 0.9f * a2[3] + 0.1f * bfhi(hq2.y);
        z2[4] = 0.9f * a2[4] + 0.1f * bflo(hq2.z);
        z2[5] = 0.9f * a2[5] + 0.1f * bfhi(hq2.z);
        z2[6] = 0.9f * a2[6] + 0.1f * bflo(hq2.w);
        z2[7] = 0.9f * a2[7] + 0.1f * bfhi(hq2.w);
        z3[0] = 0.9f * a3[0] + 0.1f * bflo(hq3.x);
        z3[1] = 0.9f * a3[1] + 0.1f * bfhi(hq3.x);
        z3[2] = 0.9f * a3[2] + 0.1f * bflo(hq3.y);
        z3[3] = 0.9f * a3[3] + 0.1f * bfhi(hq3.y);
        z3[4] = 0.9f * a3[4] + 0.1f * bflo(hq3.z);
        z3[5] = 0.9f * a3[5] + 0.1f * bfhi(hq3.z);
        z3[6] = 0.9f * a3[6] + 0.1f * bflo(hq3.w);
        z3[7] = 0.9f * a3[7] + 0.1f * bfhi(hq3.w);

        // r_c = sum_k z_k * W'[k][c], c = lane
        float g00 = 0.f, g01 = 0.f, g10 = 0.f, g11 = 0.f;
        float g20 = 0.f, g21 = 0.f, g30 = 0.f, g31 = 0.f;
#pragma unroll
        for (int k8 = 0; k8 < 8; ++k8) {
            uint4 wp = Wp[k8 * 64 + lane];
            float w0 = bflo(wp.x), w1 = bfhi(wp.x), w2 = bflo(wp.y), w3 = bfhi(wp.y);
            float w4 = bflo(wp.z), w5 = bfhi(wp.z), w6 = bflo(wp.w), w7 = bfhi(wp.w);
            g00 = fmaf(rl(z0[0], k8), w0, g00); g01 = fmaf(rl(z0[1], k8), w1, g01);
            g00 = fmaf(rl(z0[2], k8), w2, g00); g01 = fmaf(rl(z0[3], k8), w3, g01);
            g00 = fmaf(rl(z0[4], k8), w4, g00); g01 = fmaf(rl(z0[5], k8), w5, g01);
            g00 = fmaf(rl(z0[6], k8), w6, g00); g01 = fmaf(rl(z0[7], k8), w7, g01);
            g10 = fmaf(rl(z1[0], k8), w0, g10); g11 = fmaf(rl(z1[1], k8), w1, g11);
            g10 = fmaf(rl(z1[2], k8), w2, g10); g11 = fmaf(rl(z1[3], k8), w3, g11);
            g10 = fmaf(rl(z1[4], k8), w4, g10); g11 = fmaf(rl(z1[5], k8), w5, g11);
            g10 = fmaf(rl(z1[6], k8), w6, g10); g11 = fmaf(rl(z1[7], k8), w7, g11);
            g20 = fmaf(rl(z2[0], k8), w0, g20); g21 = fmaf(rl(z2[1], k8), w1, g21);
            g20 = fmaf(rl(z2[2], k8), w2, g20); g21 = fmaf(rl(z2[3], k8), w3, g21);
            g20 = fmaf(rl(z2[4], k8), w4, g20); g21 = fmaf(rl(z2[5], k8), w5, g21);
            g20 = fmaf(rl(z2[6], k8), w6, g20); g21 = fmaf(rl(z2[7], k8), w7, g21);
            g30 = fmaf(rl(z3[0], k8), w0, g30); g31 = fmaf(rl(z3[1], k8), w1, g31);
            g30 = fmaf(rl(z3[2], k8), w2, g30); g31 = fmaf(rl(z3[3], k8), w3, g31);
            g30 = fmaf(rl(z3[4], k8), w4, g30); g31 = fmaf(rl(z3[5], k8), w5, g31);
            g30 = fmaf(rl(z3[6], k8), w6, g30); g31 = fmaf(rl(z3[7], k8), w7, g31);
        }
        float r0 = fmaxf(g00 + g01, 0.f);
        float r1 = fmaxf(g10 + g11, 0.f);
        float r2 = fmaxf(g20 + g21, 0.f);
        float r3 = fmaxf(g30 + g31, 0.f);
        float r0n = pairswap(r0), r1n = pairswap(r1);
        float r2n = pairswap(r2), r3n = pairswap(r3);
        if ((lane & 1) == 0) {
            hout[(size_t)n0 * 32 + (lane >> 1)] = bfpack(r0, r0n);
            if (v1) hout[(size_t)n1 * 32 + (lane >> 1)] = bfpack(r1, r1n);
            if (v2) hout[(size_t)n2 * 32 + (lane >> 1)] = bfpack(r2, r2n);
            if (v3) hout[(size_t)n3 * 32 + (lane >> 1)] = bfpack(r3, r3n);
        }
    }
}

// ---- output projection: out = h @ lin1_w^T + b --------------------------
__global__ __launch_bounds__(256) void k_lin1(const unsigned* __restrict__ h,
                                              const float* __restrict__ w,
                                              const float* __restrict__ b,
                                              float* __restrict__ out, int N) {
    __shared__ float Wt[HID * 65];
    for (int i = threadIdx.x; i < HID * HID; i += 256) {
        int o = i >> 6, k = i & 63;
        Wt[k * 65 + o] = w[i];
    }
    __syncthreads();
    int lane = threadIdx.x & 63;
    int wid = (blockIdx.x * blockDim.x + threadIdx.x) >> 6;
    int nw = (gridDim.x * blockDim.x) >> 6;
    float bias = b[lane];
    for (int n0 = wid; n0 < N; n0 += 2 * nw) {
        int n1 = n0 + nw;
        bool v1 = n1 < N;
        int n1c = v1 ? n1 : n0;
        unsigned ua = h[(size_t)n0 * 32 + (lane >> 1)];
        unsigned ub = h[(size_t)n1c * 32 + (lane >> 1)];
        float ha = (lane & 1) ? bfhi(ua) : bflo(ua);
        float hb = (lane & 1) ? bfhi(ub) : bflo(ub);
        float acc0 = bias, acc1 = bias;
#pragma unroll
        for (int k = 0; k < 64; ++k) {
            float wv = Wt[k * 65 + lane];
            acc0 = fmaf(rl(ha, k), wv, acc0);
            acc1 = fmaf(rl(hb, k), wv, acc1);
        }
        out[(size_t)n0 * HID + lane] = acc0;
        if (v1) out[(size_t)n1 * HID + lane] = acc1;
    }
}

extern "C" void kernel_launch(void* const* d_in, const int* in_sizes, int n_in,
                              void* d_out, int out_size, void* d_ws, size_t ws_size,
                              hipStream_t stream) {
    const float* x      = (const float*)d_in[0];
    const int*   ei     = (const int*)d_in[1];
    const float* lin0_w = (const float*)d_in[2];
    const float* lin0_b = (const float*)d_in[3];
    const float* lin1_w = (const float*)d_in[4];
    const float* lin1_b = (const float*)d_in[5];
    const float* conv_w = (const float*)d_in[6];

    int N = in_sizes[0] / IN_C;
    int E = in_sizes[1] / 2;
    const int* src = ei;
    const int* dst = ei + E;

    // bf16 state buffers: N*64*2B = N*32 uints each
    unsigned* h0 = (unsigned*)d_ws;
    unsigned* hA = h0 + (size_t)N * 32;
    unsigned* hB = hA + (size_t)N * 32;
    int* row_ptr    = (int*)(hB + (size_t)N * 32);
    int* cursor     = row_ptr + (N + 1);
    int* col_idx    = cursor + N;
    int* chunk_sums = col_idx + E;

    int nch = (N + 1023) / 1024;

    // CSR build
    hipMemsetAsync(cursor, 0, (size_t)N * sizeof(int), stream);
    k_hist<<<(E + 255) / 256, 256, 0, stream>>>(dst, cursor, E);
    k_scan_block<<<nch, 1024, 0, stream>>>(cursor, row_ptr, chunk_sums, N);
    k_scan_fix<<<nch, 1024, 0, stream>>>(row_ptr, chunk_sums, N, E);
    hipMemsetAsync(cursor, 0, (size_t)N * sizeof(int), stream);
    k_fill<<<(E + 255) / 256, 256, 0, stream>>>(src, dst, row_ptr, cursor, col_idx, E);

    // input projection -> h0 (bf16)
    k_lin0<<<1024, 256, 0, stream>>>(x, lin0_w, lin0_b, h0, N);

    // 16 fused layers
    const unsigned* cur = h0;
    for (int l = 0; l < 16; ++l) {
        float beta = (float)log(0.5 / (double)(l + 1) + 1.0);
        unsigned* nxt = (l & 1) ? hB : hA;
        k_layer<<<2048, 256, 0, stream>>>((const uint4*)cur, (const uint4*)h0, nxt,
                                          conv_w + (size_t)l * HID * HID,
                                          row_ptr, col_idx, beta, N);
        cur = nxt;
    }

    // output projection
    k_lin1<<<1024, 256, 0, stream>>>(cur, lin1_w, lin1_b, (float*)d_out, N);
}